// Round 21
// baseline (803.358 us; speedup 1.0000x reference)
//
#include <hip/hip_runtime.h>
#include <hip/hip_bf16.h>

#define D 64
#define R 128
#define NSTEPS 8
#define SELU_SCALE 1.0507009873554805f
#define SELU_ALPHA 1.6732632423543772f
#define PADH 72    // fp16 stage tile pitch (agg C->A transpose, once per wave)
#define PADR 136   // ro transpose tile pitch (fp16), 272B = 17x16B aligned

typedef _Float16 half8 __attribute__((ext_vector_type(8)));
typedef _Float16 half4 __attribute__((ext_vector_type(4)));
typedef float f32x4 __attribute__((ext_vector_type(4)));

__device__ __forceinline__ float fast_sig(float x) {
    return __fdividef(1.0f, 1.0f + __expf(-x));
}
__device__ __forceinline__ float fast_tanh(float x) {
    float xc = fminf(fmaxf(x, -15.0f), 15.0f);
    float e = __expf(2.0f * xc);
    return 1.0f - __fdividef(2.0f, e + 1.0f);
}

// ---------------------------------------------------------------------------
// Prep: weight swizzles (fp32 [K][N] -> fp16 MFMA B-fragment order)
// ---------------------------------------------------------------------------
__global__ __launch_bounds__(256) void swizzle_all(
    const float* __restrict__ Wm, const float* __restrict__ Wu,
    const float* __restrict__ Uu, const float* __restrict__ Wr,
    const float* __restrict__ Ur,
    _Float16* __restrict__ wWm, _Float16* __restrict__ wWu,
    _Float16* __restrict__ wUu, _Float16* __restrict__ wWr,
    _Float16* __restrict__ wUr)
{
    const float* src; _Float16* dst; int K, N;
    switch (blockIdx.y) {
        case 0: src = Wm; dst = wWm; K = 128; N = 64;  break;
        case 1: src = Wu; dst = wWu; K = 64;  N = 192; break;
        case 2: src = Uu; dst = wUu; K = 64;  N = 192; break;
        case 3: src = Wr; dst = wWr; K = 64;  N = 384; break;
        default: src = Ur; dst = wUr; K = 128; N = 384; break;
    }
    int idx = blockIdx.x * 256 + threadIdx.x;
    int KT = K >> 5;
    int total = KT * (N >> 4) * 512;
    if (idx >= total) return;
    int j = idx & 7;
    int lane = (idx >> 3) & 63;
    int kt = (idx >> 9) % KT;
    int nt = idx / (512 * KT);
    int k = 32 * kt + 8 * (lane >> 4) + j;
    int n = 16 * nt + (lane & 15);
    dst[idx] = (_Float16)src[(size_t)k * N + n];
}

__global__ __launch_bounds__(256) void h16_init(const float* __restrict__ src,
                                                _Float16* __restrict__ dst, int n) {
    int i = blockIdx.x * 256 + threadIdx.x;
    if (i < n) dst[i] = (_Float16)src[i];
}

__global__ __launch_bounds__(192) void bias_pack(const float* __restrict__ bu,
                                                 const float* __restrict__ brr,
                                                 float4* __restrict__ biasU,
                                                 float4* __restrict__ biasR) {
    int c = threadIdx.x;
    if (c < 64) {
        biasU[c] = make_float4(bu[c] + bu[192 + c], bu[64 + c] + bu[256 + c],
                               bu[128 + c], bu[320 + c]);
    } else {
        int cr = c - 64;
        biasR[cr] = make_float4(brr[cr] + brr[384 + cr], brr[128 + cr] + brr[512 + cr],
                                brr[256 + cr], brr[640 + cr]);
    }
}

// ---------------------------------------------------------------------------
// CSR build: hist -> 3-kernel scan -> scatter -> bucket sort -> fs pack
// bucket_sort makes perm DETERMINISTIC across graph replays.
// ---------------------------------------------------------------------------
__global__ __launch_bounds__(256) void hist_kernel(const int* __restrict__ second,
                                                   int* __restrict__ cnt, int M) {
    int m = blockIdx.x * 256 + threadIdx.x;
    if (m < M) atomicAdd(&cnt[second[m]], 1);
}

__global__ __launch_bounds__(256) void scan_bsum(const int* __restrict__ cnt,
                                                 int* __restrict__ bsum, int E) {
    int i = blockIdx.x * 256 + threadIdx.x;
    int tid = threadIdx.x;
    int v = (i < E) ? cnt[i] : 0;
    __shared__ int s[256];
    s[tid] = v;
    __syncthreads();
    #pragma unroll
    for (int d = 1; d < 256; d <<= 1) {
        int t = (tid >= d) ? s[tid - d] : 0;
        __syncthreads();
        s[tid] += t;
        __syncthreads();
    }
    if (tid == 255) bsum[blockIdx.x] = s[255];
}

__global__ __launch_bounds__(1024) void scan_part(int* __restrict__ bsum, int NB) {
    int tid = threadIdx.x;
    __shared__ int s[1024];
    int v = (tid < NB) ? bsum[tid] : 0;
    s[tid] = v;
    __syncthreads();
    #pragma unroll
    for (int d = 1; d < 1024; d <<= 1) {
        int t = (tid >= d) ? s[tid - d] : 0;
        __syncthreads();
        s[tid] += t;
        __syncthreads();
    }
    if (tid < NB) bsum[tid] = s[tid] - v;   // exclusive
}

__global__ __launch_bounds__(256) void scan_final(const int* __restrict__ cnt,
                                                  const int* __restrict__ bsum,
                                                  int* __restrict__ off, int E) {
    int i = blockIdx.x * 256 + threadIdx.x;
    int tid = threadIdx.x;
    int v = (i < E) ? cnt[i] : 0;
    __shared__ int s[256];
    s[tid] = v;
    __syncthreads();
    #pragma unroll
    for (int d = 1; d < 256; d <<= 1) {
        int t = (tid >= d) ? s[tid - d] : 0;
        __syncthreads();
        s[tid] += t;
        __syncthreads();
    }
    if (i < E) off[i] = bsum[blockIdx.x] + s[tid] - v;
}

__global__ __launch_bounds__(256) void scatter_kernel(const int* __restrict__ second,
                                                      const int* __restrict__ off,
                                                      int* __restrict__ cur,
                                                      int* __restrict__ perm, int M) {
    int m = blockIdx.x * 256 + threadIdx.x;
    if (m < M) {
        int s = second[m];
        int p = atomicAdd(&cur[s], 1);
        perm[off[s] + p] = m;
    }
}

// insertion-sort each edge's bucket -> perm deterministic (ascending m)
__global__ __launch_bounds__(256) void bucket_sort(const int* __restrict__ off,
                                                   int* __restrict__ perm,
                                                   int E, int M) {
    int e = blockIdx.x * 256 + threadIdx.x;
    if (e >= E) return;
    int a = off[e];
    int b = (e == E - 1) ? M : off[e + 1];
    for (int i = a + 1; i < b; ++i) {
        int key = perm[i];
        int j = i - 1;
        while (j >= a && perm[j] > key) {
            perm[j + 1] = perm[j];
            --j;
        }
        perm[j + 1] = key;
    }
}

__global__ __launch_bounds__(256) void fs_pack(const int* __restrict__ first,
                                               const int* __restrict__ second,
                                               const int* __restrict__ perm,
                                               int2* __restrict__ fs, int M) {
    int m = blockIdx.x * 256 + threadIdx.x;
    if (m < M) {
        int pm = perm[m];
        fs[m] = make_int2(first[pm], second[pm]);
    }
}

// ---------------------------------------------------------------------------
// Phase A: msg + update-GRU. hin = hseq[t], hout = hseq[t+1].
// Wave owns 16 edges. Segmented aggregation done ON THE MATRIX CORE:
// agg[e][n] += S[e][m]*msg[m][n] via v_mfma_f32_16x16x16_f16 per col-tile,
// where B = selu'd msg C-fragment (direct register reuse: B[k=4hi+j][l15]
// == C[row=4hi+r][l15]) and A = 0/1 selection built from skey. agg lives in
// persistent f32 C-fragments; one LDS round-trip per wave converts to the
// update-GRU A-layout. No stage/agg tiles, no serial run-sum.
// ---------------------------------------------------------------------------
__global__ __launch_bounds__(256) void msg_upd(
    const _Float16* __restrict__ hin,
    _Float16* __restrict__ hout,
    const int2* __restrict__ fs,
    const int* __restrict__ off,
    const half8* __restrict__ wBm,  // [4nt][4kt][64]
    const float* __restrict__ bm,
    const half8* __restrict__ wWu,  // [12nt][2kt][64]
    const half8* __restrict__ wUu,  // [12nt][2kt][64]
    const float4* __restrict__ biasU,
    int E, int M)
{
    __shared__ _Float16 stage_s[4][16 * PADH];
    __shared__ int skeys[4][16];

    const int wid = threadIdx.x >> 6;
    const int lane = threadIdx.x & 63;
    const int hi = lane >> 4;
    const int l15 = lane & 15;
    const int e0 = (blockIdx.x * 4 + wid) * 16;

    _Float16* stageH = stage_s[wid];
    int* skey = skeys[wid];

    half8 Bm[4][4];
    #pragma unroll
    for (int nt = 0; nt < 4; ++nt)
        #pragma unroll
        for (int kt = 0; kt < 4; ++kt)
            Bm[nt][kt] = wBm[(nt * 4 + kt) * 64 + lane];

    if (e0 >= E) return;

    // persistent agg C-fragments (f32), accumulated by the S-MFMAs
    f32x4 agg[4];
    #pragma unroll
    for (int nt = 0; nt < 4; ++nt) agg[nt] = (f32x4){0.f, 0.f, 0.f, 0.f};

    // ---- message phase ----
    {
        int b = min(e0 + 16, E);
        int mstart = off[e0];
        int mend = (b == E) ? M : off[b];
        int nch = (mend > mstart) ? ((mend - mstart + 15) >> 4) : 0;

        int2 pcur = make_int2(0, 0);
        if (nch > 0) pcur = fs[min(mstart + l15, mend - 1)];

        #pragma unroll 1
        for (int ch = 0; ch < nch; ++ch) {
            int2 pnext = pcur;
            if (ch + 1 < nch)
                pnext = fs[min(mstart + (ch + 1) * 16 + l15, mend - 1)];

            const half8* fr = reinterpret_cast<const half8*>(hin + (size_t)pcur.x * D);
            const half8* sr = reinterpret_cast<const half8*>(hin + (size_t)pcur.y * D);
            half8 A[4];
            A[0] = fr[hi];
            A[1] = fr[4 + hi];
            A[2] = sr[hi];
            A[3] = sr[4 + hi];

            f32x4 acc[4];
            #pragma unroll
            for (int nt = 0; nt < 4; ++nt) acc[nt] = (f32x4){0.f, 0.f, 0.f, 0.f};
            #pragma unroll
            for (int nt = 0; nt < 4; ++nt)
                #pragma unroll
                for (int kt = 0; kt < 4; ++kt)
                    acc[nt] = __builtin_amdgcn_mfma_f32_16x16x32_f16(A[kt], Bm[nt][kt], acc[nt], 0, 0, 0);

            // selection matrix fragment: S[e=l15][m=4*hi+j]
            {
                int mrow = mstart + ch * 16 + l15;
                if (lane < 16) skey[lane] = (mrow < mend) ? (pcur.y - e0) : -1;
            }
            half4 Sf;
            #pragma unroll
            for (int j = 0; j < 4; ++j)
                Sf[j] = (skey[4 * hi + j] == l15) ? (_Float16)1.0f : (_Float16)0.0f;

            // selu -> B fragments (direct C-frag reuse), S-MFMA accumulate
            #pragma unroll
            for (int nt = 0; nt < 4; ++nt) {
                int n = nt * 16 + l15;
                float bias = bm[n];
                half4 Bf;
                #pragma unroll
                for (int r = 0; r < 4; ++r) {
                    float v = acc[nt][r] + bias;
                    v = (v > 0.0f) ? (SELU_SCALE * v)
                                   : (SELU_SCALE * SELU_ALPHA) * (__expf(v) - 1.0f);
                    Bf[r] = (_Float16)v;
                }
                agg[nt] = __builtin_amdgcn_mfma_f32_16x16x16f16(Sf, Bf, agg[nt], 0, 0, 0);
            }

            pcur = pnext;
        }
    }

    // ---- agg C-layout -> stage -> A-layout AX (once per wave) ----
    #pragma unroll
    for (int nt = 0; nt < 4; ++nt)
        #pragma unroll
        for (int r = 0; r < 4; ++r)
            stageH[(hi * 4 + r) * PADH + nt * 16 + l15] = (_Float16)agg[nt][r];

    const int ec = min(e0 + l15, E - 1);

    half8 AX[2], AHu[2];
    #pragma unroll
    for (int kt = 0; kt < 2; ++kt) {
        AX[kt] = *reinterpret_cast<const half8*>(&stageH[l15 * PADH + 32 * kt + 8 * hi]);
        AHu[kt] = reinterpret_cast<const half8*>(hin + (size_t)ec * D)[4 * kt + hi];
    }

    // ---- update GRU; h' -> hout ----
    #pragma unroll 1
    for (int i = 0; i < 4; ++i) {
        half8 WBz[2], WBr[2], WBc[2], UBz[2], UBr[2], UBc[2];
        #pragma unroll
        for (int kt = 0; kt < 2; ++kt) {
            WBz[kt] = wWu[((0 + i) * 2 + kt) * 64 + lane];
            WBr[kt] = wWu[((4 + i) * 2 + kt) * 64 + lane];
            WBc[kt] = wWu[((8 + i) * 2 + kt) * 64 + lane];
            UBz[kt] = wUu[((0 + i) * 2 + kt) * 64 + lane];
            UBr[kt] = wUu[((4 + i) * 2 + kt) * 64 + lane];
            UBc[kt] = wUu[((8 + i) * 2 + kt) * 64 + lane];
        }
        int n = 16 * i + l15;
        float4 bU = biasU[n];

        f32x4 az  = (f32x4){0.f, 0.f, 0.f, 0.f};
        f32x4 ar_ = (f32x4){0.f, 0.f, 0.f, 0.f};
        f32x4 acx = (f32x4){0.f, 0.f, 0.f, 0.f};
        f32x4 ach = (f32x4){0.f, 0.f, 0.f, 0.f};
        #pragma unroll
        for (int kt = 0; kt < 2; ++kt) {
            az  = __builtin_amdgcn_mfma_f32_16x16x32_f16(AX[kt], WBz[kt], az, 0, 0, 0);
            az  = __builtin_amdgcn_mfma_f32_16x16x32_f16(AHu[kt], UBz[kt], az, 0, 0, 0);
            ar_ = __builtin_amdgcn_mfma_f32_16x16x32_f16(AX[kt], WBr[kt], ar_, 0, 0, 0);
            ar_ = __builtin_amdgcn_mfma_f32_16x16x32_f16(AHu[kt], UBr[kt], ar_, 0, 0, 0);
            acx = __builtin_amdgcn_mfma_f32_16x16x32_f16(AX[kt], WBc[kt], acx, 0, 0, 0);
            ach = __builtin_amdgcn_mfma_f32_16x16x32_f16(AHu[kt], UBc[kt], ach, 0, 0, 0);
        }
        #pragma unroll
        for (int r = 0; r < 4; ++r) {
            int e = e0 + hi * 4 + r;
            int ecl = min(e, E - 1);
            float z = fast_sig(az[r] + bU.x);
            float rr = fast_sig(ar_[r] + bU.y);
            float c = fast_tanh(acx[r] + bU.z + rr * (ach[r] + bU.w));
            float hp = (float)hin[(size_t)ecl * D + n];
            float hn = z * hp + (1.0f - z) * c;
            if (e < E) hout[(size_t)e * D + n] = (_Float16)hn;
        }
    }
}

// ---------------------------------------------------------------------------
// Phase B: wave-specialized readout GRU. Block = 8 waves = 16 edges.
// Wave w owns output tile w: 18 weight fragments persistent in registers.
// Double-buffered rotile -> ONE barrier per step. t=0 U-phase skipped.
// AXt software-pipelined. Final Dense(1) fused.
// ---------------------------------------------------------------------------
__global__ __launch_bounds__(512, 2) void ro_all(
    const _Float16* __restrict__ hseq1,   // hseq[1]; step t at +t*edelems
    const int* __restrict__ gid,
    const float* __restrict__ Wout,
    const half8* __restrict__ wWr,  // [24nt][2kt][64]
    const half8* __restrict__ wUr,  // [24nt][4kt][64]
    const float4* __restrict__ biasR,
    float* __restrict__ out,
    int E, int edelems)
{
    __shared__ _Float16 rot2[2][16 * PADR];   // double buffer, 8.5KB
    __shared__ float partials[8][16];

    const int w = threadIdx.x >> 6;      // wave id == output tile
    const int lane = threadIdx.x & 63;
    const int hi = lane >> 4;
    const int l15 = lane & 15;
    const int e0 = blockIdx.x * 16;
    const int ec = min(e0 + l15, E - 1);

    // persistent weights for this wave's tile (loaded once)
    half8 WBz[2], WBr[2], WBx[2], UBz[4], UBr[4], UBh[4];
    #pragma unroll
    for (int kt = 0; kt < 2; ++kt) {
        WBz[kt] = wWr[((0 + w) * 2 + kt) * 64 + lane];
        WBr[kt] = wWr[((8 + w) * 2 + kt) * 64 + lane];
        WBx[kt] = wWr[((16 + w) * 2 + kt) * 64 + lane];
    }
    #pragma unroll
    for (int kt = 0; kt < 4; ++kt) {
        UBz[kt] = wUr[((0 + w) * 4 + kt) * 64 + lane];
        UBr[kt] = wUr[((8 + w) * 4 + kt) * 64 + lane];
        UBh[kt] = wUr[((16 + w) * 4 + kt) * 64 + lane];
    }
    const int c = w * 16 + l15;
    const float4 bR = biasR[c];

    half8 hp = {};   // [0..3] = C-frag of this wave's 16 cols (rows 4*hi+r)

    // prime the AXt pipeline (t = 0)
    half8 AXt[2];
    #pragma unroll
    for (int kt = 0; kt < 2; ++kt)
        AXt[kt] = reinterpret_cast<const half8*>(hseq1 + (size_t)ec * D)[4 * kt + hi];

    #pragma unroll 1
    for (int t = 0; t < NSTEPS; ++t) {
        f32x4 az  = (f32x4){0.f, 0.f, 0.f, 0.f};
        f32x4 ar_ = (f32x4){0.f, 0.f, 0.f, 0.f};
        f32x4 acx = (f32x4){0.f, 0.f, 0.f, 0.f};
        f32x4 ach = (f32x4){0.f, 0.f, 0.f, 0.f};
        #pragma unroll
        for (int kt = 0; kt < 2; ++kt) {
            az  = __builtin_amdgcn_mfma_f32_16x16x32_f16(AXt[kt], WBz[kt], az, 0, 0, 0);
            ar_ = __builtin_amdgcn_mfma_f32_16x16x32_f16(AXt[kt], WBr[kt], ar_, 0, 0, 0);
            acx = __builtin_amdgcn_mfma_f32_16x16x32_f16(AXt[kt], WBx[kt], acx, 0, 0, 0);
        }

        // AXt dead now: issue next step's loads (latency hides under U+epilogue)
        if (t + 1 < NSTEPS) {
            const _Float16* hn = hseq1 + (size_t)(t + 1) * edelems;
            #pragma unroll
            for (int kt = 0; kt < 2; ++kt)
                AXt[kt] = reinterpret_cast<const half8*>(hn + (size_t)ec * D)[4 * kt + hi];
        }

        if (t > 0) {   // state is exact zero at t=0: U-phase contributes nothing
            _Float16* rotile = rot2[t & 1];
            #pragma unroll
            for (int r = 0; r < 4; ++r)
                rotile[(hi * 4 + r) * PADR + w * 16 + l15] = hp[r];
            __syncthreads();   // RAW: writes before reads; WAR: next step's barrier

            half8 AHro[4];
            #pragma unroll
            for (int kt = 0; kt < 4; ++kt)
                AHro[kt] = *reinterpret_cast<const half8*>(&rotile[l15 * PADR + 32 * kt + 8 * hi]);

            #pragma unroll
            for (int kt = 0; kt < 4; ++kt) {
                az  = __builtin_amdgcn_mfma_f32_16x16x32_f16(AHro[kt], UBz[kt], az, 0, 0, 0);
                ar_ = __builtin_amdgcn_mfma_f32_16x16x32_f16(AHro[kt], UBr[kt], ar_, 0, 0, 0);
                ach = __builtin_amdgcn_mfma_f32_16x16x32_f16(AHro[kt], UBh[kt], ach, 0, 0, 0);
            }
        }

        #pragma unroll
        for (int r = 0; r < 4; ++r) {
            float z = fast_sig(az[r] + bR.x);
            float rr = fast_sig(ar_[r] + bR.y);
            float cc = fast_tanh(acx[r] + bR.z + rr * (ach[r] + bR.w));
            float hpf = (float)hp[r];
            hp[r] = (_Float16)(z * hpf + (1.0f - z) * cc);
        }
    }

    // ---- fused output: this wave's 16-col partial dot, then block reduce ----
    const float wv = Wout[c];
    float part[4];
    #pragma unroll
    for (int r = 0; r < 4; ++r) part[r] = (float)hp[r] * wv;
    #pragma unroll
    for (int d = 1; d < 16; d <<= 1) {
        #pragma unroll
        for (int r = 0; r < 4; ++r)
            part[r] += __shfl_xor(part[r], d);
    }
    if (l15 == 0) {
        #pragma unroll
        for (int r = 0; r < 4; ++r)
            partials[w][hi * 4 + r] = part[r];
    }
    __syncthreads();
    if (w == 0 && lane < 16) {
        float s = 0.0f;
        #pragma unroll
        for (int ww = 0; ww < 8; ++ww) s += partials[ww][lane];
        int e = e0 + lane;
        if (e < E) unsafeAtomicAdd(out + gid[e], s);
    }
}

// ---------------------------------------------------------------------------
__global__ void out_init_kernel(float* __restrict__ out, const float* __restrict__ b_out, int G) {
    int g = blockIdx.x * blockDim.x + threadIdx.x;
    if (g < G) out[g] = b_out[0];
}

// ---------------------------------------------------------------------------
extern "C" void kernel_launch(void* const* d_in, const int* in_sizes, int n_in,
                              void* d_out, int out_size, void* d_ws, size_t ws_size,
                              hipStream_t stream) {
    const float* link_state = (const float*)d_in[0];
    const int*   first      = (const int*)d_in[1];
    const int*   second     = (const int*)d_in[2];
    const int*   gids       = (const int*)d_in[3];
    const float* Wm         = (const float*)d_in[5];
    const float* bm         = (const float*)d_in[6];
    const float* Wu         = (const float*)d_in[7];
    const float* Uu         = (const float*)d_in[8];
    const float* bu         = (const float*)d_in[9];
    const float* Wr         = (const float*)d_in[10];
    const float* Ur         = (const float*)d_in[11];
    const float* brb        = (const float*)d_in[12];
    const float* Wout       = (const float*)d_in[13];
    const float* bout       = (const float*)d_in[14];

    const int E = in_sizes[0] / D;
    const int M = in_sizes[1];
    const int G = out_size;

    char* p = (char*)d_ws;
    auto carve = [&](size_t bytes) {
        void* r = (void*)p;
        p += (bytes + 255) & ~(size_t)255;
        return r;
    };
    const size_t edelems = (size_t)E * D;
    _Float16*  hseq  = (_Float16*)carve(edelems * 2 * (NSTEPS + 1));  // 9 states
    int*       perm  = (int*)carve((size_t)M * 4);
    int2*      fs    = (int2*)carve((size_t)M * 8);
    int*       cnt   = (int*)carve((size_t)E * 4);
    int*       cur   = (int*)carve((size_t)E * 4);
    int*       off   = (int*)carve((size_t)(E + 1) * 4);
    int*       bsum  = (int*)carve(4096 * 4);
    _Float16*  wWm   = (_Float16*)carve(8192 * 2);
    _Float16*  wWu   = (_Float16*)carve(12288 * 2);
    _Float16*  wUu   = (_Float16*)carve(12288 * 2);
    _Float16*  wWr   = (_Float16*)carve(24576 * 2);
    _Float16*  wUr   = (_Float16*)carve(49152 * 2);
    float4*    biasU = (float4*)carve(64 * 16);
    float4*    biasR = (float4*)carve(128 * 16);

    hipMemsetAsync(cnt, 0, (size_t)E * 4, stream);
    hipMemsetAsync(cur, 0, (size_t)E * 4, stream);

    h16_init<<<(E * D + 255) / 256, 256, 0, stream>>>(link_state, hseq, E * D);
    swizzle_all<<<dim3(192, 5), 256, 0, stream>>>(Wm, Wu, Uu, Wr, Ur,
                                                  wWm, wWu, wUu, wWr, wUr);
    bias_pack<<<1, 192, 0, stream>>>(bu, brb, biasU, biasR);

    const int NB = (E + 255) / 256;
    hist_kernel<<<(M + 255) / 256, 256, 0, stream>>>(second, cnt, M);
    scan_bsum<<<NB, 256, 0, stream>>>(cnt, bsum, E);
    scan_part<<<1, 1024, 0, stream>>>(bsum, NB);
    scan_final<<<NB, 256, 0, stream>>>(cnt, bsum, off, E);
    scatter_kernel<<<(M + 255) / 256, 256, 0, stream>>>(second, off, cur, perm, M);
    bucket_sort<<<NB, 256, 0, stream>>>(off, perm, E, M);
    fs_pack<<<(M + 255) / 256, 256, 0, stream>>>(first, second, perm, fs, M);

    const int e_blocks = (E + 63) / 64;

    // Phase A: 8 x (msg + update GRU), writing the state history
    for (int t = 0; t < NSTEPS; ++t) {
        msg_upd<<<e_blocks, 256, 0, stream>>>(hseq + (size_t)t * edelems,
                                              hseq + (size_t)(t + 1) * edelems,
                                              fs, off,
                                              (const half8*)wWm, bm,
                                              (const half8*)wWu, (const half8*)wUu, biasU,
                                              E, M);
    }

    // Output init, then Phase B: wave-specialized readout (16 edges/block)
    out_init_kernel<<<(G + 255) / 256, 256, 0, stream>>>((float*)d_out, bout, G);
    const int ro_blocks = (E + 15) / 16;
    ro_all<<<ro_blocks, 512, 0, stream>>>(hseq + edelems, gids, Wout,
                                          (const half8*)wWr, (const half8*)wUr, biasR,
                                          (float*)d_out, E, (int)edelems);
}

// Round 22
// 751.724 us; speedup vs baseline: 1.0687x; 1.0687x over previous
//
#include <hip/hip_runtime.h>
#include <hip/hip_bf16.h>

#define D 64
#define R 128
#define NSTEPS 8
#define SELU_SCALE 1.0507009873554805f
#define SELU_ALPHA 1.6732632423543772f
#define PADH 72    // fp16 stage tile pitch
#define PADF 68    // f32 agg tile pitch (4*68 = 16 mod 32 -> conflict-free)
#define PADR 136   // ro transpose tile pitch (fp16), 272B = 17x16B aligned

typedef _Float16 half8 __attribute__((ext_vector_type(8)));
typedef float f32x4 __attribute__((ext_vector_type(4)));

__device__ __forceinline__ float fast_sig(float x) {
    return __fdividef(1.0f, 1.0f + __expf(-x));
}
__device__ __forceinline__ float fast_tanh(float x) {
    float xc = fminf(fmaxf(x, -15.0f), 15.0f);
    float e = __expf(2.0f * xc);
    return 1.0f - __fdividef(2.0f, e + 1.0f);
}

// ---------------------------------------------------------------------------
// Prep: weight swizzles (fp32 [K][N] -> fp16 MFMA B-fragment order)
// ---------------------------------------------------------------------------
__global__ __launch_bounds__(256) void swizzle_all(
    const float* __restrict__ Wm, const float* __restrict__ Wu,
    const float* __restrict__ Uu, const float* __restrict__ Wr,
    const float* __restrict__ Ur,
    _Float16* __restrict__ wWm, _Float16* __restrict__ wWu,
    _Float16* __restrict__ wUu, _Float16* __restrict__ wWr,
    _Float16* __restrict__ wUr)
{
    const float* src; _Float16* dst; int K, N;
    switch (blockIdx.y) {
        case 0: src = Wm; dst = wWm; K = 128; N = 64;  break;
        case 1: src = Wu; dst = wWu; K = 64;  N = 192; break;
        case 2: src = Uu; dst = wUu; K = 64;  N = 192; break;
        case 3: src = Wr; dst = wWr; K = 64;  N = 384; break;
        default: src = Ur; dst = wUr; K = 128; N = 384; break;
    }
    int idx = blockIdx.x * 256 + threadIdx.x;
    int KT = K >> 5;
    int total = KT * (N >> 4) * 512;
    if (idx >= total) return;
    int j = idx & 7;
    int lane = (idx >> 3) & 63;
    int kt = (idx >> 9) % KT;
    int nt = idx / (512 * KT);
    int k = 32 * kt + 8 * (lane >> 4) + j;
    int n = 16 * nt + (lane & 15);
    dst[idx] = (_Float16)src[(size_t)k * N + n];
}

__global__ __launch_bounds__(256) void h16_init(const float* __restrict__ src,
                                                _Float16* __restrict__ dst, int n) {
    int i = blockIdx.x * 256 + threadIdx.x;
    if (i < n) dst[i] = (_Float16)src[i];
}

__global__ __launch_bounds__(192) void bias_pack(const float* __restrict__ bu,
                                                 const float* __restrict__ brr,
                                                 float4* __restrict__ biasU,
                                                 float4* __restrict__ biasR) {
    int c = threadIdx.x;
    if (c < 64) {
        biasU[c] = make_float4(bu[c] + bu[192 + c], bu[64 + c] + bu[256 + c],
                               bu[128 + c], bu[320 + c]);
    } else {
        int cr = c - 64;
        biasR[cr] = make_float4(brr[cr] + brr[384 + cr], brr[128 + cr] + brr[512 + cr],
                                brr[256 + cr], brr[640 + cr]);
    }
}

// ---------------------------------------------------------------------------
// CSR build: hist -> 3-kernel scan -> scatter -> bucket sort -> fs pack
// bucket_sort makes perm DETERMINISTIC across graph replays.
// ---------------------------------------------------------------------------
__global__ __launch_bounds__(256) void hist_kernel(const int* __restrict__ second,
                                                   int* __restrict__ cnt, int M) {
    int m = blockIdx.x * 256 + threadIdx.x;
    if (m < M) atomicAdd(&cnt[second[m]], 1);
}

__global__ __launch_bounds__(256) void scan_bsum(const int* __restrict__ cnt,
                                                 int* __restrict__ bsum, int E) {
    int i = blockIdx.x * 256 + threadIdx.x;
    int tid = threadIdx.x;
    int v = (i < E) ? cnt[i] : 0;
    __shared__ int s[256];
    s[tid] = v;
    __syncthreads();
    #pragma unroll
    for (int d = 1; d < 256; d <<= 1) {
        int t = (tid >= d) ? s[tid - d] : 0;
        __syncthreads();
        s[tid] += t;
        __syncthreads();
    }
    if (tid == 255) bsum[blockIdx.x] = s[255];
}

__global__ __launch_bounds__(1024) void scan_part(int* __restrict__ bsum, int NB) {
    int tid = threadIdx.x;
    __shared__ int s[1024];
    int v = (tid < NB) ? bsum[tid] : 0;
    s[tid] = v;
    __syncthreads();
    #pragma unroll
    for (int d = 1; d < 1024; d <<= 1) {
        int t = (tid >= d) ? s[tid - d] : 0;
        __syncthreads();
        s[tid] += t;
        __syncthreads();
    }
    if (tid < NB) bsum[tid] = s[tid] - v;   // exclusive
}

__global__ __launch_bounds__(256) void scan_final(const int* __restrict__ cnt,
                                                  const int* __restrict__ bsum,
                                                  int* __restrict__ off, int E) {
    int i = blockIdx.x * 256 + threadIdx.x;
    int tid = threadIdx.x;
    int v = (i < E) ? cnt[i] : 0;
    __shared__ int s[256];
    s[tid] = v;
    __syncthreads();
    #pragma unroll
    for (int d = 1; d < 256; d <<= 1) {
        int t = (tid >= d) ? s[tid - d] : 0;
        __syncthreads();
        s[tid] += t;
        __syncthreads();
    }
    if (i < E) off[i] = bsum[blockIdx.x] + s[tid] - v;
}

__global__ __launch_bounds__(256) void scatter_kernel(const int* __restrict__ second,
                                                      const int* __restrict__ off,
                                                      int* __restrict__ cur,
                                                      int* __restrict__ perm, int M) {
    int m = blockIdx.x * 256 + threadIdx.x;
    if (m < M) {
        int s = second[m];
        int p = atomicAdd(&cur[s], 1);
        perm[off[s] + p] = m;
    }
}

// insertion-sort each edge's bucket -> perm deterministic (ascending m)
__global__ __launch_bounds__(256) void bucket_sort(const int* __restrict__ off,
                                                   int* __restrict__ perm,
                                                   int E, int M) {
    int e = blockIdx.x * 256 + threadIdx.x;
    if (e >= E) return;
    int a = off[e];
    int b = (e == E - 1) ? M : off[e + 1];
    for (int i = a + 1; i < b; ++i) {
        int key = perm[i];
        int j = i - 1;
        while (j >= a && perm[j] > key) {
            perm[j + 1] = perm[j];
            --j;
        }
        perm[j + 1] = key;
    }
}

__global__ __launch_bounds__(256) void fs_pack(const int* __restrict__ first,
                                               const int* __restrict__ second,
                                               const int* __restrict__ perm,
                                               int2* __restrict__ fs, int M) {
    int m = blockIdx.x * 256 + threadIdx.x;
    if (m < M) {
        int pm = perm[m];
        fs[m] = make_int2(first[pm], second[pm]);
    }
}

// ---------------------------------------------------------------------------
// Phase A: msg + update-GRU. hin = hseq[t], hout = hseq[t+1].
// Wave owns 16 edges; CSR-contiguous message slice. Stage tile fp16, agg
// tile f32. fs for chunk ch+1 prefetched at top of chunk ch.
// ---------------------------------------------------------------------------
__global__ __launch_bounds__(256) void msg_upd(
    const _Float16* __restrict__ hin,
    _Float16* __restrict__ hout,
    const int2* __restrict__ fs,
    const int* __restrict__ off,
    const half8* __restrict__ wBm,  // [4nt][4kt][64]
    const float* __restrict__ bm,
    const half8* __restrict__ wWu,  // [12nt][2kt][64]
    const half8* __restrict__ wUu,  // [12nt][2kt][64]
    const float4* __restrict__ biasU,
    int E, int M)
{
    __shared__ _Float16 stage_s[4][16 * PADH];
    __shared__ float aggF_s[4][16 * PADF];
    __shared__ int skeys[4][16];

    const int wid = threadIdx.x >> 6;
    const int lane = threadIdx.x & 63;
    const int hi = lane >> 4;
    const int l15 = lane & 15;
    const int e0 = (blockIdx.x * 4 + wid) * 16;

    _Float16* stageH = stage_s[wid];
    float* aggF = aggF_s[wid];
    int* skey = skeys[wid];

    #pragma unroll
    for (int m = 0; m < 16; ++m)
        aggF[m * PADF + lane] = 0.0f;

    half8 Bm[4][4];
    #pragma unroll
    for (int nt = 0; nt < 4; ++nt)
        #pragma unroll
        for (int kt = 0; kt < 4; ++kt)
            Bm[nt][kt] = wBm[(nt * 4 + kt) * 64 + lane];

    if (e0 >= E) return;

    // ---- message phase ----
    {
        int b = min(e0 + 16, E);
        int mstart = off[e0];
        int mend = (b == E) ? M : off[b];
        int nch = (mend > mstart) ? ((mend - mstart + 15) >> 4) : 0;

        int2 pcur = make_int2(0, 0);
        if (nch > 0) pcur = fs[min(mstart + l15, mend - 1)];

        #pragma unroll 1
        for (int ch = 0; ch < nch; ++ch) {
            int2 pnext = pcur;
            if (ch + 1 < nch)
                pnext = fs[min(mstart + (ch + 1) * 16 + l15, mend - 1)];

            const half8* fr = reinterpret_cast<const half8*>(hin + (size_t)pcur.x * D);
            const half8* sr = reinterpret_cast<const half8*>(hin + (size_t)pcur.y * D);
            half8 A[4];
            A[0] = fr[hi];
            A[1] = fr[4 + hi];
            A[2] = sr[hi];
            A[3] = sr[4 + hi];

            f32x4 acc[4];
            #pragma unroll
            for (int nt = 0; nt < 4; ++nt) acc[nt] = (f32x4){0.f, 0.f, 0.f, 0.f};
            #pragma unroll
            for (int nt = 0; nt < 4; ++nt)
                #pragma unroll
                for (int kt = 0; kt < 4; ++kt)
                    acc[nt] = __builtin_amdgcn_mfma_f32_16x16x32_f16(A[kt], Bm[nt][kt], acc[nt], 0, 0, 0);

            #pragma unroll
            for (int nt = 0; nt < 4; ++nt) {
                int n = nt * 16 + l15;
                float bias = bm[n];
                #pragma unroll
                for (int r = 0; r < 4; ++r) {
                    float v = acc[nt][r] + bias;
                    v = (v > 0.0f) ? (SELU_SCALE * v)
                                   : (SELU_SCALE * SELU_ALPHA) * (__expf(v) - 1.0f);
                    stageH[(hi * 4 + r) * PADH + n] = (_Float16)v;
                }
            }
            {
                int mrow = mstart + ch * 16 + l15;
                if (lane < 16) skey[lane] = (mrow < mend) ? (pcur.y - e0) : -1;
            }

            // segmented run-sum in f32 (deterministic order after bucket_sort)
            float run = 0.0f;
            int kprev = skey[0];
            #pragma unroll
            for (int m = 0; m < 16; ++m) {
                int km = skey[m];
                if (km != kprev) {
                    if (kprev >= 0) aggF[kprev * PADF + lane] += run;
                    run = 0.0f;
                    kprev = km;
                }
                run += (float)stageH[m * PADH + lane];
            }
            if (kprev >= 0) aggF[kprev * PADF + lane] += run;

            pcur = pnext;
        }
    }

    const int ec = min(e0 + l15, E - 1);

    half8 AX[2], AHu[2];
    #pragma unroll
    for (int kt = 0; kt < 2; ++kt) {
        const float* s = aggF + l15 * PADF + 32 * kt + 8 * hi;
        half8 ax;
        #pragma unroll
        for (int j = 0; j < 8; ++j) ax[j] = (_Float16)s[j];
        AX[kt] = ax;
        AHu[kt] = reinterpret_cast<const half8*>(hin + (size_t)ec * D)[4 * kt + hi];
    }

    // ---- update GRU; h' -> hout ----
    #pragma unroll 1
    for (int i = 0; i < 4; ++i) {
        half8 WBz[2], WBr[2], WBc[2], UBz[2], UBr[2], UBc[2];
        #pragma unroll
        for (int kt = 0; kt < 2; ++kt) {
            WBz[kt] = wWu[((0 + i) * 2 + kt) * 64 + lane];
            WBr[kt] = wWu[((4 + i) * 2 + kt) * 64 + lane];
            WBc[kt] = wWu[((8 + i) * 2 + kt) * 64 + lane];
            UBz[kt] = wUu[((0 + i) * 2 + kt) * 64 + lane];
            UBr[kt] = wUu[((4 + i) * 2 + kt) * 64 + lane];
            UBc[kt] = wUu[((8 + i) * 2 + kt) * 64 + lane];
        }
        int n = 16 * i + l15;
        float4 bU = biasU[n];

        f32x4 az  = (f32x4){0.f, 0.f, 0.f, 0.f};
        f32x4 ar_ = (f32x4){0.f, 0.f, 0.f, 0.f};
        f32x4 acx = (f32x4){0.f, 0.f, 0.f, 0.f};
        f32x4 ach = (f32x4){0.f, 0.f, 0.f, 0.f};
        #pragma unroll
        for (int kt = 0; kt < 2; ++kt) {
            az  = __builtin_amdgcn_mfma_f32_16x16x32_f16(AX[kt], WBz[kt], az, 0, 0, 0);
            az  = __builtin_amdgcn_mfma_f32_16x16x32_f16(AHu[kt], UBz[kt], az, 0, 0, 0);
            ar_ = __builtin_amdgcn_mfma_f32_16x16x32_f16(AX[kt], WBr[kt], ar_, 0, 0, 0);
            ar_ = __builtin_amdgcn_mfma_f32_16x16x32_f16(AHu[kt], UBr[kt], ar_, 0, 0, 0);
            acx = __builtin_amdgcn_mfma_f32_16x16x32_f16(AX[kt], WBc[kt], acx, 0, 0, 0);
            ach = __builtin_amdgcn_mfma_f32_16x16x32_f16(AHu[kt], UBc[kt], ach, 0, 0, 0);
        }
        #pragma unroll
        for (int r = 0; r < 4; ++r) {
            int e = e0 + hi * 4 + r;
            int ecl = min(e, E - 1);
            float z = fast_sig(az[r] + bU.x);
            float rr = fast_sig(ar_[r] + bU.y);
            float c = fast_tanh(acx[r] + bU.z + rr * (ach[r] + bU.w));
            float hp = (float)hin[(size_t)ecl * D + n];
            float hn = z * hp + (1.0f - z) * c;
            if (e < E) hout[(size_t)e * D + n] = (_Float16)hn;
        }
    }
}

// ---------------------------------------------------------------------------
// Phase B: wave-specialized readout GRU. Block = 8 waves = 16 edges.
// Wave w owns output tile w: 18 weight fragments persistent in registers.
// Double-buffered rotile -> ONE barrier per step. t=0 U-phase skipped.
// AXt software-pipelined: next step's x fragments issued right after the
// current W-MFMAs consume them. Final Dense(1) fused.
// ---------------------------------------------------------------------------
__global__ __launch_bounds__(512, 2) void ro_all(
    const _Float16* __restrict__ hseq1,   // hseq[1]; step t at +t*edelems
    const int* __restrict__ gid,
    const float* __restrict__ Wout,
    const half8* __restrict__ wWr,  // [24nt][2kt][64]
    const half8* __restrict__ wUr,  // [24nt][4kt][64]
    const float4* __restrict__ biasR,
    float* __restrict__ out,
    int E, int edelems)
{
    __shared__ _Float16 rot2[2][16 * PADR];   // double buffer, 8.5KB
    __shared__ float partials[8][16];

    const int w = threadIdx.x >> 6;      // wave id == output tile
    const int lane = threadIdx.x & 63;
    const int hi = lane >> 4;
    const int l15 = lane & 15;
    const int e0 = blockIdx.x * 16;
    const int ec = min(e0 + l15, E - 1);

    // persistent weights for this wave's tile (loaded once)
    half8 WBz[2], WBr[2], WBx[2], UBz[4], UBr[4], UBh[4];
    #pragma unroll
    for (int kt = 0; kt < 2; ++kt) {
        WBz[kt] = wWr[((0 + w) * 2 + kt) * 64 + lane];
        WBr[kt] = wWr[((8 + w) * 2 + kt) * 64 + lane];
        WBx[kt] = wWr[((16 + w) * 2 + kt) * 64 + lane];
    }
    #pragma unroll
    for (int kt = 0; kt < 4; ++kt) {
        UBz[kt] = wUr[((0 + w) * 4 + kt) * 64 + lane];
        UBr[kt] = wUr[((8 + w) * 4 + kt) * 64 + lane];
        UBh[kt] = wUr[((16 + w) * 4 + kt) * 64 + lane];
    }
    const int c = w * 16 + l15;
    const float4 bR = biasR[c];

    half8 hp = {};   // [0..3] = C-frag of this wave's 16 cols (rows 4*hi+r)

    // prime the AXt pipeline (t = 0)
    half8 AXt[2];
    #pragma unroll
    for (int kt = 0; kt < 2; ++kt)
        AXt[kt] = reinterpret_cast<const half8*>(hseq1 + (size_t)ec * D)[4 * kt + hi];

    #pragma unroll 1
    for (int t = 0; t < NSTEPS; ++t) {
        f32x4 az  = (f32x4){0.f, 0.f, 0.f, 0.f};
        f32x4 ar_ = (f32x4){0.f, 0.f, 0.f, 0.f};
        f32x4 acx = (f32x4){0.f, 0.f, 0.f, 0.f};
        f32x4 ach = (f32x4){0.f, 0.f, 0.f, 0.f};
        #pragma unroll
        for (int kt = 0; kt < 2; ++kt) {
            az  = __builtin_amdgcn_mfma_f32_16x16x32_f16(AXt[kt], WBz[kt], az, 0, 0, 0);
            ar_ = __builtin_amdgcn_mfma_f32_16x16x32_f16(AXt[kt], WBr[kt], ar_, 0, 0, 0);
            acx = __builtin_amdgcn_mfma_f32_16x16x32_f16(AXt[kt], WBx[kt], acx, 0, 0, 0);
        }

        // AXt dead now: issue next step's loads (latency hides under U+epilogue)
        if (t + 1 < NSTEPS) {
            const _Float16* hn = hseq1 + (size_t)(t + 1) * edelems;
            #pragma unroll
            for (int kt = 0; kt < 2; ++kt)
                AXt[kt] = reinterpret_cast<const half8*>(hn + (size_t)ec * D)[4 * kt + hi];
        }

        if (t > 0) {   // state is exact zero at t=0: U-phase contributes nothing
            _Float16* rotile = rot2[t & 1];
            #pragma unroll
            for (int r = 0; r < 4; ++r)
                rotile[(hi * 4 + r) * PADR + w * 16 + l15] = hp[r];
            __syncthreads();   // RAW: writes before reads; WAR: next step's barrier

            half8 AHro[4];
            #pragma unroll
            for (int kt = 0; kt < 4; ++kt)
                AHro[kt] = *reinterpret_cast<const half8*>(&rotile[l15 * PADR + 32 * kt + 8 * hi]);

            #pragma unroll
            for (int kt = 0; kt < 4; ++kt) {
                az  = __builtin_amdgcn_mfma_f32_16x16x32_f16(AHro[kt], UBz[kt], az, 0, 0, 0);
                ar_ = __builtin_amdgcn_mfma_f32_16x16x32_f16(AHro[kt], UBr[kt], ar_, 0, 0, 0);
                ach = __builtin_amdgcn_mfma_f32_16x16x32_f16(AHro[kt], UBh[kt], ach, 0, 0, 0);
            }
        }

        #pragma unroll
        for (int r = 0; r < 4; ++r) {
            float z = fast_sig(az[r] + bR.x);
            float rr = fast_sig(ar_[r] + bR.y);
            float cc = fast_tanh(acx[r] + bR.z + rr * (ach[r] + bR.w));
            float hpf = (float)hp[r];
            hp[r] = (_Float16)(z * hpf + (1.0f - z) * cc);
        }
    }

    // ---- fused output: this wave's 16-col partial dot, then block reduce ----
    const float wv = Wout[c];
    float part[4];
    #pragma unroll
    for (int r = 0; r < 4; ++r) part[r] = (float)hp[r] * wv;
    #pragma unroll
    for (int d = 1; d < 16; d <<= 1) {
        #pragma unroll
        for (int r = 0; r < 4; ++r)
            part[r] += __shfl_xor(part[r], d);
    }
    if (l15 == 0) {
        #pragma unroll
        for (int r = 0; r < 4; ++r)
            partials[w][hi * 4 + r] = part[r];
    }
    __syncthreads();
    if (w == 0 && lane < 16) {
        float s = 0.0f;
        #pragma unroll
        for (int ww = 0; ww < 8; ++ww) s += partials[ww][lane];
        int e = e0 + lane;
        if (e < E) unsafeAtomicAdd(out + gid[e], s);
    }
}

// ---------------------------------------------------------------------------
__global__ void out_init_kernel(float* __restrict__ out, const float* __restrict__ b_out, int G) {
    int g = blockIdx.x * blockDim.x + threadIdx.x;
    if (g < G) out[g] = b_out[0];
}

// ---------------------------------------------------------------------------
extern "C" void kernel_launch(void* const* d_in, const int* in_sizes, int n_in,
                              void* d_out, int out_size, void* d_ws, size_t ws_size,
                              hipStream_t stream) {
    const float* link_state = (const float*)d_in[0];
    const int*   first      = (const int*)d_in[1];
    const int*   second     = (const int*)d_in[2];
    const int*   gids       = (const int*)d_in[3];
    const float* Wm         = (const float*)d_in[5];
    const float* bm         = (const float*)d_in[6];
    const float* Wu         = (const float*)d_in[7];
    const float* Uu         = (const float*)d_in[8];
    const float* bu         = (const float*)d_in[9];
    const float* Wr         = (const float*)d_in[10];
    const float* Ur         = (const float*)d_in[11];
    const float* brb        = (const float*)d_in[12];
    const float* Wout       = (const float*)d_in[13];
    const float* bout       = (const float*)d_in[14];

    const int E = in_sizes[0] / D;
    const int M = in_sizes[1];
    const int G = out_size;

    char* p = (char*)d_ws;
    auto carve = [&](size_t bytes) {
        void* r = (void*)p;
        p += (bytes + 255) & ~(size_t)255;
        return r;
    };
    const size_t edelems = (size_t)E * D;
    _Float16*  hseq  = (_Float16*)carve(edelems * 2 * (NSTEPS + 1));  // 9 states
    int*       perm  = (int*)carve((size_t)M * 4);
    int2*      fs    = (int2*)carve((size_t)M * 8);
    int*       cnt   = (int*)carve((size_t)E * 4);
    int*       cur   = (int*)carve((size_t)E * 4);
    int*       off   = (int*)carve((size_t)(E + 1) * 4);
    int*       bsum  = (int*)carve(4096 * 4);
    _Float16*  wWm   = (_Float16*)carve(8192 * 2);
    _Float16*  wWu   = (_Float16*)carve(12288 * 2);
    _Float16*  wUu   = (_Float16*)carve(12288 * 2);
    _Float16*  wWr   = (_Float16*)carve(24576 * 2);
    _Float16*  wUr   = (_Float16*)carve(49152 * 2);
    float4*    biasU = (float4*)carve(64 * 16);
    float4*    biasR = (float4*)carve(128 * 16);

    hipMemsetAsync(cnt, 0, (size_t)E * 4, stream);
    hipMemsetAsync(cur, 0, (size_t)E * 4, stream);

    h16_init<<<(E * D + 255) / 256, 256, 0, stream>>>(link_state, hseq, E * D);
    swizzle_all<<<dim3(192, 5), 256, 0, stream>>>(Wm, Wu, Uu, Wr, Ur,
                                                  wWm, wWu, wUu, wWr, wUr);
    bias_pack<<<1, 192, 0, stream>>>(bu, brb, biasU, biasR);

    const int NB = (E + 255) / 256;
    hist_kernel<<<(M + 255) / 256, 256, 0, stream>>>(second, cnt, M);
    scan_bsum<<<NB, 256, 0, stream>>>(cnt, bsum, E);
    scan_part<<<1, 1024, 0, stream>>>(bsum, NB);
    scan_final<<<NB, 256, 0, stream>>>(cnt, bsum, off, E);
    scatter_kernel<<<(M + 255) / 256, 256, 0, stream>>>(second, off, cur, perm, M);
    bucket_sort<<<NB, 256, 0, stream>>>(off, perm, E, M);
    fs_pack<<<(M + 255) / 256, 256, 0, stream>>>(first, second, perm, fs, M);

    const int e_blocks = (E + 63) / 64;

    // Phase A: 8 x (msg + update GRU), writing the state history
    for (int t = 0; t < NSTEPS; ++t) {
        msg_upd<<<e_blocks, 256, 0, stream>>>(hseq + (size_t)t * edelems,
                                              hseq + (size_t)(t + 1) * edelems,
                                              fs, off,
                                              (const half8*)wWm, bm,
                                              (const half8*)wWu, (const half8*)wUu, biasU,
                                              E, M);
    }

    // Output init, then Phase B: wave-specialized readout (16 edges/block)
    out_init_kernel<<<(G + 255) / 256, 256, 0, stream>>>((float*)d_out, bout, G);
    const int ro_blocks = (E + 15) / 16;
    ro_all<<<ro_blocks, 512, 0, stream>>>(hseq + edelems, gids, Wout,
                                          (const half8*)wWr, (const half8*)wUr, biasR,
                                          (float*)d_out, E, (int)edelems);
}